// Round 1
// baseline (1631.490 us; speedup 1.0000x reference)
//
#include <hip/hip_runtime.h>
#include <math.h>

#define B_SZ 2
#define L_SZ 2048
#define DMODEL 1024
#define DINNER 2048
#define DSTATE 16
#define DTRANK 64
#define M_ROWS (B_SZ * L_SZ)   // 4096

__device__ __forceinline__ float softplusf(float x) {
    // numerically stable: max(x,0) + log1p(exp(-|x|))
    return fmaxf(x, 0.f) + log1pf(expf(-fabsf(x)));
}
__device__ __forceinline__ float siluf(float x) {
    return x * (1.f / (1.f + expf(-x)));
}

// ---------------------------------------------------------------------------
// Generic fp32 GEMM, C[M,N] = A[M,K] * B[N,K]^T  (both row-major, K-contig)
// EPI: 0 = plain store, 1 = softplus(acc + bias[n])
// ---------------------------------------------------------------------------
template <int BM, int BN, int BK, int TM, int TN, bool BOUND_N, int EPI>
__global__ __launch_bounds__(256) void gemm_nt(
    const float* __restrict__ A, int lda,
    const float* __restrict__ Bmat, int ldb,
    float* __restrict__ C, int ldc,
    int M, int N, int K, const float* __restrict__ bias)
{
    __shared__ float As[BK][BM + 4];
    __shared__ float Bs[BK][BN + 4];

    const int tid = threadIdx.x;
    const int tx = tid % (BN / TN);   // n-direction
    const int ty = tid / (BN / TN);   // m-direction
    const int m0 = blockIdx.y * BM;
    const int n0 = blockIdx.x * BN;

    float acc[TM][TN];
#pragma unroll
    for (int i = 0; i < TM; ++i)
#pragma unroll
        for (int j = 0; j < TN; ++j) acc[i][j] = 0.f;

    for (int k0 = 0; k0 < K; k0 += BK) {
        // stage A tile (transposed into LDS: As[k][m])
        for (int idx = tid * 4; idx < BM * BK; idx += 256 * 4) {
            int row = idx / BK;
            int kk = idx % BK;
            float4 v = *(const float4*)&A[(size_t)(m0 + row) * lda + k0 + kk];
            As[kk + 0][row] = v.x;
            As[kk + 1][row] = v.y;
            As[kk + 2][row] = v.z;
            As[kk + 3][row] = v.w;
        }
        // stage B tile
        for (int idx = tid * 4; idx < BN * BK; idx += 256 * 4) {
            int row = idx / BK;
            int kk = idx % BK;
            float4 v;
            if (!BOUND_N || (n0 + row) < N)
                v = *(const float4*)&Bmat[(size_t)(n0 + row) * ldb + k0 + kk];
            else
                v = make_float4(0.f, 0.f, 0.f, 0.f);
            Bs[kk + 0][row] = v.x;
            Bs[kk + 1][row] = v.y;
            Bs[kk + 2][row] = v.z;
            Bs[kk + 3][row] = v.w;
        }
        __syncthreads();

#pragma unroll
        for (int k = 0; k < BK; ++k) {
            float a[TM], b[TN];
#pragma unroll
            for (int i = 0; i < TM; ++i) a[i] = As[k][ty * TM + i];
#pragma unroll
            for (int j = 0; j < TN; ++j) b[j] = Bs[k][tx * TN + j];
#pragma unroll
            for (int i = 0; i < TM; ++i)
#pragma unroll
                for (int j = 0; j < TN; ++j) acc[i][j] = fmaf(a[i], b[j], acc[i][j]);
        }
        __syncthreads();
    }

#pragma unroll
    for (int i = 0; i < TM; ++i) {
        int m = m0 + ty * TM + i;
#pragma unroll
        for (int j = 0; j < TN; ++j) {
            int n = n0 + tx * TN + j;
            if (BOUND_N && n >= N) continue;
            float v = acc[i][j];
            if (EPI == 1) v = softplusf(v + bias[n]);
            C[(size_t)m * ldc + n] = v;
        }
    }
}

// ---------------------------------------------------------------------------
// Causal depthwise conv (width 4) + SiLU.  Reads xs = xz[:, :, 0:2048].
// ---------------------------------------------------------------------------
__global__ __launch_bounds__(256) void conv_silu_kernel(
    const float* __restrict__ xz, const float* __restrict__ cw,
    const float* __restrict__ cb, float* __restrict__ u)
{
    int i = blockIdx.x * 256 + threadIdx.x;   // over M_ROWS*DINNER
    int d = i % DINNER;
    int bl = i / DINNER;
    int b = bl / L_SZ;
    int l = bl % L_SZ;
    float acc = cb[d];
#pragma unroll
    for (int k = 0; k < 4; ++k) {
        int ls = l + k - 3;
        if (ls >= 0)
            acc = fmaf(xz[(size_t)(b * L_SZ + ls) * 4096 + d], cw[d * 4 + k], acc);
    }
    u[i] = siluf(acc);
}

// ---------------------------------------------------------------------------
// Selective scan. 16 lanes per channel (lane = state index n).
// Block = 256 threads = 16 channels; grid = 256 blocks (B*DINNER/16).
// LDS-tiles 16 timesteps; writes y (+ u*D skip) in-place into dbuf.
// ---------------------------------------------------------------------------
__global__ __launch_bounds__(256) void scan_kernel(
    const float* __restrict__ dbuf_in, const float* __restrict__ ubuf,
    const float* __restrict__ xdbl, const float* __restrict__ A_log,
    const float* __restrict__ Dv, float* __restrict__ ybuf)
{
    __shared__ float sd[16][16];
    __shared__ float su[16][16];
    __shared__ float sB[16][17];
    __shared__ float sC[16][17];

    const int tid = threadIdx.x;
    const int g0 = blockIdx.x * 16;       // first channel of this block
    const int b = g0 / DINNER;            // blocks never straddle b (2048%16==0)
    const int d0 = g0 % DINNER;
    const int dg = tid >> 4;              // local channel 0..15
    const int n = tid & 15;               // state index 0..15
    const int d = d0 + dg;

    const float Acoef = -expf(A_log[d * DSTATE + n]);
    const float Dd = Dv[d];
    float h = 0.f;

    const size_t base_bl = (size_t)b * L_SZ;
    // loader mapping: thread loads (step = dg, elem = n)
    float r_d = dbuf_in[(base_bl + dg) * DINNER + d0 + n];
    float r_u = ubuf[(base_bl + dg) * DINNER + d0 + n];
    float r_B = xdbl[(base_bl + dg) * 96 + 64 + n];
    float r_C = xdbl[(base_bl + dg) * 96 + 80 + n];

    for (int l0 = 0; l0 < L_SZ; l0 += 16) {
        sd[dg][n] = r_d;
        su[dg][n] = r_u;
        sB[dg][n] = r_B;
        sC[dg][n] = r_C;
        __syncthreads();

        if (l0 + 16 < L_SZ) {   // prefetch next tile while computing
            int l1 = l0 + 16 + dg;
            r_d = dbuf_in[(base_bl + l1) * DINNER + d0 + n];
            r_u = ubuf[(base_bl + l1) * DINNER + d0 + n];
            r_B = xdbl[(base_bl + l1) * 96 + 64 + n];
            r_C = xdbl[(base_bl + l1) * 96 + 80 + n];
        }

#pragma unroll
        for (int s = 0; s < 16; ++s) {
            float dl = sd[s][dg];
            float ul = su[s][dg];
            float Bv = sB[s][n];
            float Cv = sC[s][n];
            float dA = expf(dl * Acoef);
            h = fmaf(dA, h, dl * ul * Bv);
            float p = h * Cv;
            p += __shfl_xor(p, 1);
            p += __shfl_xor(p, 2);
            p += __shfl_xor(p, 4);
            p += __shfl_xor(p, 8);
            if (n == 0)
                ybuf[(base_bl + l0 + s) * DINNER + d] = fmaf(ul, Dd, p);
        }
        __syncthreads();
    }
}

// ---------------------------------------------------------------------------
// y *= silu(res), in place.  res = xz[:, :, 2048:4096]
// ---------------------------------------------------------------------------
__global__ __launch_bounds__(256) void gate_kernel(
    float* __restrict__ ybuf, const float* __restrict__ xz)
{
    int i = blockIdx.x * 256 + threadIdx.x;
    int d = i % DINNER;
    int bl = i / DINNER;
    float res = xz[(size_t)bl * 4096 + 2048 + d];
    ybuf[i] = ybuf[i] * siluf(res);
}

// ---------------------------------------------------------------------------
extern "C" void kernel_launch(void* const* d_in, const int* in_sizes, int n_in,
                              void* d_out, int out_size, void* d_ws, size_t ws_size,
                              hipStream_t stream)
{
    const float* x          = (const float*)d_in[0];
    const float* in_proj_w  = (const float*)d_in[1];
    const float* conv_w     = (const float*)d_in[2];
    const float* conv_b     = (const float*)d_in[3];
    const float* x_proj_w   = (const float*)d_in[4];
    const float* dt_proj_w  = (const float*)d_in[5];
    const float* dt_proj_b  = (const float*)d_in[6];
    const float* A_log      = (const float*)d_in[7];
    const float* Dv         = (const float*)d_in[8];
    const float* out_proj_w = (const float*)d_in[9];
    float* out = (float*)d_out;

    // workspace layout (floats):
    float* ws   = (float*)d_ws;
    float* xz   = ws;                                   // 4096*4096 = 64 MB
    float* u    = xz + (size_t)M_ROWS * 4096;           // 4096*2048 = 32 MB
    float* dbuf = u + (size_t)M_ROWS * 2048;            // 4096*2048 = 32 MB (delta, then y)
    float* xdbl = dbuf + (size_t)M_ROWS * 2048;         // 4096*96   = 1.5 MB

    // 1) in_proj: xz[M,4096] = x[M,1024] @ in_proj_w[4096,1024]^T
    {
        dim3 g(4096 / 128, M_ROWS / 128);
        gemm_nt<128, 128, 16, 8, 8, false, 0><<<g, 256, 0, stream>>>(
            x, 1024, in_proj_w, 1024, xz, 4096, M_ROWS, 4096, 1024, nullptr);
    }
    // 2) causal depthwise conv + silu -> u[M,2048]
    conv_silu_kernel<<<(M_ROWS * DINNER) / 256, 256, 0, stream>>>(xz, conv_w, conv_b, u);
    // 3) x_proj: xdbl[M,96] = u @ x_proj_w[96,2048]^T
    {
        dim3 g(1, M_ROWS / 32);
        gemm_nt<32, 128, 16, 2, 8, true, 0><<<g, 256, 0, stream>>>(
            u, 2048, x_proj_w, 2048, xdbl, 96, M_ROWS, 96, 2048, nullptr);
    }
    // 4) dt_proj + softplus: dbuf[M,2048] = softplus(xdbl[:, :64] @ dt_proj_w^T + b)
    {
        dim3 g(2048 / 128, M_ROWS / 128);
        gemm_nt<128, 128, 16, 8, 8, false, 1><<<g, 256, 0, stream>>>(
            xdbl, 96, dt_proj_w, 64, dbuf, 2048, M_ROWS, 2048, 64, dt_proj_b);
    }
    // 5) selective scan: dbuf <- y + u*D   (in place over delta)
    scan_kernel<<<B_SZ * DINNER / 16, 256, 0, stream>>>(dbuf, u, xdbl, A_log, Dv, dbuf);
    // 6) gate: dbuf *= silu(res)
    gate_kernel<<<(M_ROWS * DINNER) / 256, 256, 0, stream>>>(dbuf, xz);
    // 7) out_proj: out[M,1024] = dbuf @ out_proj_w[1024,2048]^T
    {
        dim3 g(1024 / 128, M_ROWS / 128);
        gemm_nt<128, 128, 16, 8, 8, false, 0><<<g, 256, 0, stream>>>(
            dbuf, 2048, out_proj_w, 2048, out, 1024, M_ROWS, 1024, 2048, nullptr);
    }
}

// Round 2
// 1280.566 us; speedup vs baseline: 1.2740x; 1.2740x over previous
//
#include <hip/hip_runtime.h>
#include <math.h>

#define B_SZ 2
#define L_SZ 2048
#define DMODEL 1024
#define DINNER 2048
#define DSTATE 16
#define DTRANK 64
#define M_ROWS (B_SZ * L_SZ)   // 4096

// chunked scan config
#define CH 32                  // number of chunks along L
#define CLEN (L_SZ / CH)       // 64 timesteps per chunk
#define CPB 64                 // channels per scan block (256 thr = 64 ch x 4 lanes)

__device__ __forceinline__ float softplusf(float x) {
    return fmaxf(x, 0.f) + log1pf(expf(-fabsf(x)));
}
__device__ __forceinline__ float siluf(float x) {
    return x * (1.f / (1.f + expf(-x)));
}

// ---------------------------------------------------------------------------
// Generic fp32 GEMM, C[M,N] = A[M,K] * B[N,K]^T  (both row-major, K-contig)
// EPI: 0 = plain store, 1 = softplus(acc + bias[n])
// ---------------------------------------------------------------------------
template <int BM, int BN, int BK, int TM, int TN, bool BOUND_N, int EPI>
__global__ __launch_bounds__(256) void gemm_nt(
    const float* __restrict__ A, int lda,
    const float* __restrict__ Bmat, int ldb,
    float* __restrict__ C, int ldc,
    int M, int N, int K, const float* __restrict__ bias)
{
    __shared__ float As[BK][BM + 4];
    __shared__ float Bs[BK][BN + 4];

    const int tid = threadIdx.x;
    const int tx = tid % (BN / TN);
    const int ty = tid / (BN / TN);
    const int m0 = blockIdx.y * BM;
    const int n0 = blockIdx.x * BN;

    float acc[TM][TN];
#pragma unroll
    for (int i = 0; i < TM; ++i)
#pragma unroll
        for (int j = 0; j < TN; ++j) acc[i][j] = 0.f;

    for (int k0 = 0; k0 < K; k0 += BK) {
        for (int idx = tid * 4; idx < BM * BK; idx += 256 * 4) {
            int row = idx / BK;
            int kk = idx % BK;
            float4 v = *(const float4*)&A[(size_t)(m0 + row) * lda + k0 + kk];
            As[kk + 0][row] = v.x;
            As[kk + 1][row] = v.y;
            As[kk + 2][row] = v.z;
            As[kk + 3][row] = v.w;
        }
        for (int idx = tid * 4; idx < BN * BK; idx += 256 * 4) {
            int row = idx / BK;
            int kk = idx % BK;
            float4 v;
            if (!BOUND_N || (n0 + row) < N)
                v = *(const float4*)&Bmat[(size_t)(n0 + row) * ldb + k0 + kk];
            else
                v = make_float4(0.f, 0.f, 0.f, 0.f);
            Bs[kk + 0][row] = v.x;
            Bs[kk + 1][row] = v.y;
            Bs[kk + 2][row] = v.z;
            Bs[kk + 3][row] = v.w;
        }
        __syncthreads();

#pragma unroll
        for (int k = 0; k < BK; ++k) {
            float a[TM], b[TN];
#pragma unroll
            for (int i = 0; i < TM; ++i) a[i] = As[k][ty * TM + i];
#pragma unroll
            for (int j = 0; j < TN; ++j) b[j] = Bs[k][tx * TN + j];
#pragma unroll
            for (int i = 0; i < TM; ++i)
#pragma unroll
                for (int j = 0; j < TN; ++j) acc[i][j] = fmaf(a[i], b[j], acc[i][j]);
        }
        __syncthreads();
    }

#pragma unroll
    for (int i = 0; i < TM; ++i) {
        int m = m0 + ty * TM + i;
#pragma unroll
        for (int j = 0; j < TN; ++j) {
            int n = n0 + tx * TN + j;
            if (BOUND_N && n >= N) continue;
            float v = acc[i][j];
            if (EPI == 1) v = softplusf(v + bias[n]);
            C[(size_t)m * ldc + n] = v;
        }
    }
}

// ---------------------------------------------------------------------------
// Causal depthwise conv (width 4) + SiLU.
// ---------------------------------------------------------------------------
__global__ __launch_bounds__(256) void conv_silu_kernel(
    const float* __restrict__ xz, const float* __restrict__ cw,
    const float* __restrict__ cb, float* __restrict__ u)
{
    int i = blockIdx.x * 256 + threadIdx.x;
    int d = i % DINNER;
    int bl = i / DINNER;
    int b = bl / L_SZ;
    int l = bl % L_SZ;
    float acc = cb[d];
#pragma unroll
    for (int k = 0; k < 4; ++k) {
        int ls = l + k - 3;
        if (ls >= 0)
            acc = fmaf(xz[(size_t)(b * L_SZ + ls) * 4096 + d], cw[d * 4 + k], acc);
    }
    u[i] = siluf(acc);
}

// ---------------------------------------------------------------------------
// Chunked selective scan.
// Thread layout: tid -> (dg = tid>>2 channel 0..63, q = tid&3 state-quad).
// Each thread owns h[4] (states 4q..4q+3) of channel d0+dg over one chunk.
// PASS3=false: from h0=0 compute P (prod dA) and S (final local h).
// PASS3=true:  seed h from Hin (stored in Sbuf by combine), emit y.
// ---------------------------------------------------------------------------
template <bool PASS3>
__global__ __launch_bounds__(256) void scan_chunk(
    const float* __restrict__ dbuf, const float* __restrict__ ubuf,
    const float* __restrict__ xdbl, const float* __restrict__ A_log,
    const float* __restrict__ Dv,
    float* __restrict__ Pbuf, float* __restrict__ Sbuf,
    float* __restrict__ ybuf)
{
    __shared__ float sd[16][CPB];
    __shared__ float su[16][CPB];
    __shared__ float sB[16][DSTATE];
    __shared__ float sC[16][DSTATE];

    const int tid = threadIdx.x;
    const int c    = blockIdx.x % CH;
    const int dblk = (blockIdx.x / CH) % (DINNER / CPB);
    const int b    = blockIdx.x / (CH * (DINNER / CPB));
    const int d0 = dblk * CPB;
    const int dg = tid >> 2;
    const int q  = tid & 3;
    const int d  = d0 + dg;
    const size_t base_bl = (size_t)b * L_SZ + (size_t)c * CLEN;

    float Ac[4], h[4], p[4];
#pragma unroll
    for (int j = 0; j < 4; ++j) {
        Ac[j] = -expf(A_log[d * DSTATE + 4 * q + j]);
        p[j] = 1.f;
    }
    const size_t psoff = (((size_t)b * CH + c) * DINNER + d0) * DSTATE + (size_t)tid * 4;
    if (PASS3) {
        float4 h0 = *(const float4*)&Sbuf[psoff];
        h[0] = h0.x; h[1] = h0.y; h[2] = h0.z; h[3] = h0.w;
    } else {
        h[0] = h[1] = h[2] = h[3] = 0.f;
    }
    const float Dd = PASS3 ? Dv[d] : 0.f;

    // cooperative loader mapping: one float4 of delta/u + one B + one C scalar
    const int ls = tid >> 4;          // step row 0..15
    const int g4 = (tid & 15) * 4;    // channel group
    const int ln = tid & 15;          // state for B/C

    float4 r_d = *(const float4*)&dbuf[(base_bl + ls) * DINNER + d0 + g4];
    float4 r_u = *(const float4*)&ubuf[(base_bl + ls) * DINNER + d0 + g4];
    float r_B = xdbl[(base_bl + ls) * 96 + 64 + ln];
    float r_C = xdbl[(base_bl + ls) * 96 + 80 + ln];

    for (int l0 = 0; l0 < CLEN; l0 += 16) {
        __syncthreads();              // previous tile fully consumed / y drained
        *(float4*)&sd[ls][g4] = r_d;
        *(float4*)&su[ls][g4] = r_u;
        sB[ls][ln] = r_B;
        sC[ls][ln] = r_C;
        __syncthreads();

        if (l0 + 16 < CLEN) {         // prefetch next tile
            r_d = *(const float4*)&dbuf[(base_bl + l0 + 16 + ls) * DINNER + d0 + g4];
            r_u = *(const float4*)&ubuf[(base_bl + l0 + 16 + ls) * DINNER + d0 + g4];
            r_B = xdbl[(base_bl + l0 + 16 + ls) * 96 + 64 + ln];
            r_C = xdbl[(base_bl + l0 + 16 + ls) * 96 + 80 + ln];
        }

#pragma unroll
        for (int s = 0; s < 16; ++s) {
            float dl = sd[s][dg];
            float ul = su[s][dg];
            float4 Bv = *(float4*)&sB[s][4 * q];
            float dbu = dl * ul;
            float dA0 = expf(dl * Ac[0]);
            float dA1 = expf(dl * Ac[1]);
            float dA2 = expf(dl * Ac[2]);
            float dA3 = expf(dl * Ac[3]);
            h[0] = fmaf(dA0, h[0], dbu * Bv.x);
            h[1] = fmaf(dA1, h[1], dbu * Bv.y);
            h[2] = fmaf(dA2, h[2], dbu * Bv.z);
            h[3] = fmaf(dA3, h[3], dbu * Bv.w);
            if (!PASS3) {
                p[0] *= dA0; p[1] *= dA1; p[2] *= dA2; p[3] *= dA3;
            } else {
                float4 Cv = *(float4*)&sC[s][4 * q];
                float y = h[0] * Cv.x + h[1] * Cv.y + h[2] * Cv.z + h[3] * Cv.w;
                y += __shfl_xor(y, 1);
                y += __shfl_xor(y, 2);
                if (q == 0) su[s][dg] = fmaf(ul, Dd, y);  // slot owner: this wave only
            }
        }

        if (PASS3) {                  // coalesced y writeout from the su tile
            __syncthreads();
            float4 yo = *(float4*)&su[ls][g4];
            *(float4*)&ybuf[(base_bl + l0 + ls) * DINNER + d0 + g4] = yo;
        }
    }

    if (!PASS3) {
        *(float4*)&Pbuf[psoff] = make_float4(p[0], p[1], p[2], p[3]);
        *(float4*)&Sbuf[psoff] = make_float4(h[0], h[1], h[2], h[3]);
    }
}

// ---------------------------------------------------------------------------
// Combine chunk states serially (32 steps per (b,d,n)).
// In-place: Sbuf[c] <- Hin (state entering chunk c).
// ---------------------------------------------------------------------------
__global__ __launch_bounds__(256) void scan_combine(
    const float* __restrict__ Pbuf, float* __restrict__ Sbuf)
{
    int t = blockIdx.x * 256 + threadIdx.x;       // 65536 threads
    int b = t >> 15;
    int rem = t & 32767;                          // (d,n) flat
    size_t base = (size_t)b * CH * DINNER * DSTATE + rem;
    float H = 0.f;
#pragma unroll 4
    for (int c = 0; c < CH; ++c) {
        size_t off = base + (size_t)c * DINNER * DSTATE;
        float S = Sbuf[off];
        float P = Pbuf[off];
        Sbuf[off] = H;
        H = fmaf(P, H, S);
    }
}

// ---------------------------------------------------------------------------
// y *= silu(res), in place.
// ---------------------------------------------------------------------------
__global__ __launch_bounds__(256) void gate_kernel(
    float* __restrict__ ybuf, const float* __restrict__ xz)
{
    int i = blockIdx.x * 256 + threadIdx.x;
    int d = i % DINNER;
    int bl = i / DINNER;
    float res = xz[(size_t)bl * 4096 + 2048 + d];
    ybuf[i] = ybuf[i] * siluf(res);
}

// ---------------------------------------------------------------------------
extern "C" void kernel_launch(void* const* d_in, const int* in_sizes, int n_in,
                              void* d_out, int out_size, void* d_ws, size_t ws_size,
                              hipStream_t stream)
{
    const float* x          = (const float*)d_in[0];
    const float* in_proj_w  = (const float*)d_in[1];
    const float* conv_w     = (const float*)d_in[2];
    const float* conv_b     = (const float*)d_in[3];
    const float* x_proj_w   = (const float*)d_in[4];
    const float* dt_proj_w  = (const float*)d_in[5];
    const float* dt_proj_b  = (const float*)d_in[6];
    const float* A_log      = (const float*)d_in[7];
    const float* Dv         = (const float*)d_in[8];
    const float* out_proj_w = (const float*)d_in[9];
    float* out = (float*)d_out;

    // workspace layout (floats): total ~145.5 MB
    float* ws   = (float*)d_ws;
    float* xz   = ws;                                   // 4096*4096
    float* u    = xz + (size_t)M_ROWS * 4096;           // 4096*2048
    float* dbuf = u + (size_t)M_ROWS * 2048;            // 4096*2048 (delta, then y)
    float* xdbl = dbuf + (size_t)M_ROWS * 2048;         // 4096*96
    float* Pbuf = xdbl + (size_t)M_ROWS * 96;           // 2*32*2048*16
    float* Sbuf = Pbuf + (size_t)B_SZ * CH * DINNER * DSTATE;

    // 1) in_proj
    {
        dim3 g(4096 / 128, M_ROWS / 128);
        gemm_nt<128, 128, 16, 8, 8, false, 0><<<g, 256, 0, stream>>>(
            x, 1024, in_proj_w, 1024, xz, 4096, M_ROWS, 4096, 1024, nullptr);
    }
    // 2) conv + silu -> u
    conv_silu_kernel<<<(M_ROWS * DINNER) / 256, 256, 0, stream>>>(xz, conv_w, conv_b, u);
    // 3) x_proj
    {
        dim3 g(1, M_ROWS / 32);
        gemm_nt<32, 128, 16, 2, 8, true, 0><<<g, 256, 0, stream>>>(
            u, 2048, x_proj_w, 2048, xdbl, 96, M_ROWS, 96, 2048, nullptr);
    }
    // 4) dt_proj + softplus -> dbuf (delta)
    {
        dim3 g(2048 / 128, M_ROWS / 128);
        gemm_nt<128, 128, 16, 8, 8, false, 1><<<g, 256, 0, stream>>>(
            xdbl, 96, dt_proj_w, 64, dbuf, 2048, M_ROWS, 2048, 64, dt_proj_b);
    }
    // 5) chunked selective scan (3 dispatches)
    {
        const int nblk = B_SZ * (DINNER / CPB) * CH;    // 2048
        scan_chunk<false><<<nblk, 256, 0, stream>>>(dbuf, u, xdbl, A_log, Dv, Pbuf, Sbuf, nullptr);
        scan_combine<<<B_SZ * DINNER * DSTATE / 256, 256, 0, stream>>>(Pbuf, Sbuf);
        scan_chunk<true><<<nblk, 256, 0, stream>>>(dbuf, u, xdbl, A_log, Dv, nullptr, Sbuf, dbuf);
    }
    // 6) gate
    gate_kernel<<<(M_ROWS * DINNER) / 256, 256, 0, stream>>>(dbuf, xz);
    // 7) out_proj
    {
        dim3 g(1024 / 128, M_ROWS / 128);
        gemm_nt<128, 128, 16, 8, 8, false, 0><<<g, 256, 0, stream>>>(
            dbuf, 2048, out_proj_w, 2048, out, 1024, M_ROWS, 1024, 2048, nullptr);
    }
}

// Round 3
// 814.956 us; speedup vs baseline: 2.0019x; 1.5713x over previous
//
#include <hip/hip_runtime.h>
#include <hip/hip_bf16.h>
#include <math.h>

#define B_SZ 2
#define L_SZ 2048
#define DMODEL 1024
#define DINNER 2048
#define DSTATE 16
#define DTRANK 64
#define M_ROWS (B_SZ * L_SZ)   // 4096

#define CH 32
#define CLEN (L_SZ / CH)
#define CPB 64

typedef short shortx8 __attribute__((ext_vector_type(8)));
typedef float floatx4 __attribute__((ext_vector_type(4)));

__device__ __forceinline__ float softplusf(float x) {
    return fmaxf(x, 0.f) + log1pf(expf(-fabsf(x)));
}
__device__ __forceinline__ float siluf(float x) {
    return x * (1.f / (1.f + expf(-x)));
}

// async global->LDS, 16 bytes per lane; LDS dst = wave-uniform base + lane*16
__device__ __forceinline__ void async_ld16(const void* g, void* l) {
    __builtin_amdgcn_global_load_lds(
        (__attribute__((address_space(1))) void*)(unsigned long long)g,
        (__attribute__((address_space(3))) void*)(unsigned int)(unsigned long long)l,
        16, 0, 0);
}

// ---------------------------------------------------------------------------
// bf16 MFMA GEMM (m97 structure): C[M,N] += A'[M,Kp] * B'[N,Kp]^T, fp32 out.
// A', B' are split-bf16 tripled-K buffers. Block=256thr=4 waves (2x2),
// tile BM x BN, BK=32, wave tile (BM/2)x(BN/2) of 16x16x32 MFMAs.
// ---------------------------------------------------------------------------
template <int BM, int BN>
__global__ __launch_bounds__(256) void gemm_bf16_nt(
    const unsigned short* __restrict__ A,
    const unsigned short* __restrict__ Bm,
    float* __restrict__ C, int ldc, int Kp)
{
    constexpr int TMW = BM / 32;   // mfma tiles per wave (m)
    constexpr int TNW = BN / 32;   // mfma tiles per wave (n)
    __shared__ unsigned short As[BM * 32];
    __shared__ unsigned short Bs[BN * 32];

    const int tid = threadIdx.x;
    const int w = tid >> 6;
    const int lane = tid & 63;
    const int wm = w >> 1, wn = w & 1;
    const int m0 = blockIdx.y * BM;
    const int n0 = blockIdx.x * BN;

    const int r4 = lane >> 2;            // row within 16-row staging group
    const int c8 = (lane & 3) * 8;       // k-offset (8 bf16 = 16B)
    const int lm = lane & 15;            // mfma row/col within tile
    const int quad = lane >> 4;          // mfma k-quad

    floatx4 acc[TMW][TNW] = {};

    for (int k0 = 0; k0 < Kp; k0 += 32) {
        // stage A tile: BM/16 instructions total, round-robin over 4 waves
#pragma unroll
        for (int jj = 0; jj < BM / 64; ++jj) {
            int j = w + jj * 4;
            const unsigned short* g = A + (size_t)(m0 + j * 16 + r4) * Kp + k0 + c8;
            async_ld16(g, &As[j * 512]);
        }
#pragma unroll
        for (int jj = 0; jj < BN / 64; ++jj) {
            int j = w + jj * 4;
            const unsigned short* g = Bm + (size_t)(n0 + j * 16 + r4) * Kp + k0 + c8;
            async_ld16(g, &Bs[j * 512]);
        }
        __syncthreads();   // drains vmcnt: LDS tiles ready

        shortx8 af[TMW], bf[TNW];
#pragma unroll
        for (int i = 0; i < TMW; ++i)
            af[i] = *(const shortx8*)&As[(wm * (BM / 2) + i * 16 + lm) * 32 + quad * 8];
#pragma unroll
        for (int j = 0; j < TNW; ++j)
            bf[j] = *(const shortx8*)&Bs[(wn * (BN / 2) + j * 16 + lm) * 32 + quad * 8];
#pragma unroll
        for (int i = 0; i < TMW; ++i)
#pragma unroll
            for (int j = 0; j < TNW; ++j)
                acc[i][j] = __builtin_amdgcn_mfma_f32_16x16x32_bf16(af[i], bf[j], acc[i][j], 0, 0, 0);
        __syncthreads();   // all waves done with LDS before restage
    }

    // epilogue: C/D layout col=lane&15, row=quad*4+reg  (m89-verified)
#pragma unroll
    for (int i = 0; i < TMW; ++i) {
#pragma unroll
        for (int r = 0; r < 4; ++r) {
            int row = m0 + wm * (BM / 2) + i * 16 + quad * 4 + r;
#pragma unroll
            for (int j = 0; j < TNW; ++j) {
                int col = n0 + wn * (BN / 2) + j * 16 + lm;
                C[(size_t)row * ldc + col] = acc[i][j][r];
            }
        }
    }
}

// ---------------------------------------------------------------------------
// fp32 -> split-bf16 tripled-K.  ORDER 0 (A-side): [hi|hi|lo]
//                                ORDER 1 (B-side): [hi|lo|hi]
// ---------------------------------------------------------------------------
template <int ORDER>
__global__ __launch_bounds__(256) void split3_kernel(
    const float* __restrict__ src, unsigned short* __restrict__ dst, int K)
{
    int i = blockIdx.x * 256 + threadIdx.x;
    int m = i / K;
    int k = i - m * K;
    float a = src[i];
    __hip_bfloat16 h = __float2bfloat16(a);
    __hip_bfloat16 l = __float2bfloat16(a - __bfloat162float(h));
    unsigned short hu = *(unsigned short*)&h;
    unsigned short lu = *(unsigned short*)&l;
    unsigned short* row = dst + (size_t)m * 3 * K;
    if (ORDER == 0) { row[k] = hu; row[K + k] = hu; row[2 * K + k] = lu; }
    else           { row[k] = hu; row[K + k] = lu; row[2 * K + k] = hu; }
}

// gate (y *= silu(res)) fused with A-side split for out_proj
__global__ __launch_bounds__(256) void gate_split3_kernel(
    const float* __restrict__ ybuf, const float* __restrict__ xz,
    unsigned short* __restrict__ dst)
{
    int i = blockIdx.x * 256 + threadIdx.x;
    int d = i % DINNER;
    int bl = i / DINNER;
    float res = xz[(size_t)bl * 4096 + 2048 + d];
    float a = ybuf[i] * siluf(res);
    __hip_bfloat16 h = __float2bfloat16(a);
    __hip_bfloat16 l = __float2bfloat16(a - __bfloat162float(h));
    unsigned short hu = *(unsigned short*)&h;
    unsigned short lu = *(unsigned short*)&l;
    unsigned short* row = dst + (size_t)bl * 3 * DINNER;
    row[d] = hu; row[DINNER + d] = hu; row[2 * DINNER + d] = lu;
}

// ---------------------------------------------------------------------------
// fp32 GEMM for the small projections (x_proj N=96, dt_proj K=64)
// ---------------------------------------------------------------------------
template <int BM, int BN, int BK, int TM, int TN, bool BOUND_N, int EPI>
__global__ __launch_bounds__(256) void gemm_nt(
    const float* __restrict__ A, int lda,
    const float* __restrict__ Bmat, int ldb,
    float* __restrict__ C, int ldc,
    int M, int N, int K, const float* __restrict__ bias)
{
    __shared__ float As[BK][BM + 4];
    __shared__ float Bs[BK][BN + 4];

    const int tid = threadIdx.x;
    const int tx = tid % (BN / TN);
    const int ty = tid / (BN / TN);
    const int m0 = blockIdx.y * BM;
    const int n0 = blockIdx.x * BN;

    float acc[TM][TN];
#pragma unroll
    for (int i = 0; i < TM; ++i)
#pragma unroll
        for (int j = 0; j < TN; ++j) acc[i][j] = 0.f;

    for (int k0 = 0; k0 < K; k0 += BK) {
        for (int idx = tid * 4; idx < BM * BK; idx += 256 * 4) {
            int row = idx / BK;
            int kk = idx % BK;
            float4 v = *(const float4*)&A[(size_t)(m0 + row) * lda + k0 + kk];
            As[kk + 0][row] = v.x;
            As[kk + 1][row] = v.y;
            As[kk + 2][row] = v.z;
            As[kk + 3][row] = v.w;
        }
        for (int idx = tid * 4; idx < BN * BK; idx += 256 * 4) {
            int row = idx / BK;
            int kk = idx % BK;
            float4 v;
            if (!BOUND_N || (n0 + row) < N)
                v = *(const float4*)&Bmat[(size_t)(n0 + row) * ldb + k0 + kk];
            else
                v = make_float4(0.f, 0.f, 0.f, 0.f);
            Bs[kk + 0][row] = v.x;
            Bs[kk + 1][row] = v.y;
            Bs[kk + 2][row] = v.z;
            Bs[kk + 3][row] = v.w;
        }
        __syncthreads();

#pragma unroll
        for (int k = 0; k < BK; ++k) {
            float a[TM], b[TN];
#pragma unroll
            for (int i = 0; i < TM; ++i) a[i] = As[k][ty * TM + i];
#pragma unroll
            for (int j = 0; j < TN; ++j) b[j] = Bs[k][tx * TN + j];
#pragma unroll
            for (int i = 0; i < TM; ++i)
#pragma unroll
                for (int j = 0; j < TN; ++j) acc[i][j] = fmaf(a[i], b[j], acc[i][j]);
        }
        __syncthreads();
    }

#pragma unroll
    for (int i = 0; i < TM; ++i) {
        int m = m0 + ty * TM + i;
#pragma unroll
        for (int j = 0; j < TN; ++j) {
            int n = n0 + tx * TN + j;
            if (BOUND_N && n >= N) continue;
            float v = acc[i][j];
            if (EPI == 1) v = softplusf(v + bias[n]);
            C[(size_t)m * ldc + n] = v;
        }
    }
}

// ---------------------------------------------------------------------------
__global__ __launch_bounds__(256) void conv_silu_kernel(
    const float* __restrict__ xz, const float* __restrict__ cw,
    const float* __restrict__ cb, float* __restrict__ u)
{
    int i = blockIdx.x * 256 + threadIdx.x;
    int d = i % DINNER;
    int bl = i / DINNER;
    int b = bl / L_SZ;
    int l = bl % L_SZ;
    float acc = cb[d];
#pragma unroll
    for (int k = 0; k < 4; ++k) {
        int ls = l + k - 3;
        if (ls >= 0)
            acc = fmaf(xz[(size_t)(b * L_SZ + ls) * 4096 + d], cw[d * 4 + k], acc);
    }
    u[i] = siluf(acc);
}

// ---------------------------------------------------------------------------
// Chunked selective scan (3 passes) — unchanged from R2.
// ---------------------------------------------------------------------------
template <bool PASS3>
__global__ __launch_bounds__(256) void scan_chunk(
    const float* __restrict__ dbuf, const float* __restrict__ ubuf,
    const float* __restrict__ xdbl, const float* __restrict__ A_log,
    const float* __restrict__ Dv,
    float* __restrict__ Pbuf, float* __restrict__ Sbuf,
    float* __restrict__ ybuf)
{
    __shared__ float sd[16][CPB];
    __shared__ float su[16][CPB];
    __shared__ float sB[16][DSTATE];
    __shared__ float sC[16][DSTATE];

    const int tid = threadIdx.x;
    const int c    = blockIdx.x % CH;
    const int dblk = (blockIdx.x / CH) % (DINNER / CPB);
    const int b    = blockIdx.x / (CH * (DINNER / CPB));
    const int d0 = dblk * CPB;
    const int dg = tid >> 2;
    const int q  = tid & 3;
    const int d  = d0 + dg;
    const size_t base_bl = (size_t)b * L_SZ + (size_t)c * CLEN;

    float Ac[4], h[4], p[4];
#pragma unroll
    for (int j = 0; j < 4; ++j) {
        Ac[j] = -expf(A_log[d * DSTATE + 4 * q + j]);
        p[j] = 1.f;
    }
    const size_t psoff = (((size_t)b * CH + c) * DINNER + d0) * DSTATE + (size_t)tid * 4;
    if (PASS3) {
        float4 h0 = *(const float4*)&Sbuf[psoff];
        h[0] = h0.x; h[1] = h0.y; h[2] = h0.z; h[3] = h0.w;
    } else {
        h[0] = h[1] = h[2] = h[3] = 0.f;
    }
    const float Dd = PASS3 ? Dv[d] : 0.f;

    const int ls = tid >> 4;
    const int g4 = (tid & 15) * 4;
    const int ln = tid & 15;

    float4 r_d = *(const float4*)&dbuf[(base_bl + ls) * DINNER + d0 + g4];
    float4 r_u = *(const float4*)&ubuf[(base_bl + ls) * DINNER + d0 + g4];
    float r_B = xdbl[(base_bl + ls) * 96 + 64 + ln];
    float r_C = xdbl[(base_bl + ls) * 96 + 80 + ln];

    for (int l0 = 0; l0 < CLEN; l0 += 16) {
        __syncthreads();
        *(float4*)&sd[ls][g4] = r_d;
        *(float4*)&su[ls][g4] = r_u;
        sB[ls][ln] = r_B;
        sC[ls][ln] = r_C;
        __syncthreads();

        if (l0 + 16 < CLEN) {
            r_d = *(const float4*)&dbuf[(base_bl + l0 + 16 + ls) * DINNER + d0 + g4];
            r_u = *(const float4*)&ubuf[(base_bl + l0 + 16 + ls) * DINNER + d0 + g4];
            r_B = xdbl[(base_bl + l0 + 16 + ls) * 96 + 64 + ln];
            r_C = xdbl[(base_bl + l0 + 16 + ls) * 96 + 80 + ln];
        }

#pragma unroll
        for (int s = 0; s < 16; ++s) {
            float dl = sd[s][dg];
            float ul = su[s][dg];
            float4 Bv = *(float4*)&sB[s][4 * q];
            float dbu = dl * ul;
            float dA0 = expf(dl * Ac[0]);
            float dA1 = expf(dl * Ac[1]);
            float dA2 = expf(dl * Ac[2]);
            float dA3 = expf(dl * Ac[3]);
            h[0] = fmaf(dA0, h[0], dbu * Bv.x);
            h[1] = fmaf(dA1, h[1], dbu * Bv.y);
            h[2] = fmaf(dA2, h[2], dbu * Bv.z);
            h[3] = fmaf(dA3, h[3], dbu * Bv.w);
            if (!PASS3) {
                p[0] *= dA0; p[1] *= dA1; p[2] *= dA2; p[3] *= dA3;
            } else {
                float4 Cv = *(float4*)&sC[s][4 * q];
                float y = h[0] * Cv.x + h[1] * Cv.y + h[2] * Cv.z + h[3] * Cv.w;
                y += __shfl_xor(y, 1);
                y += __shfl_xor(y, 2);
                if (q == 0) su[s][dg] = fmaf(ul, Dd, y);
            }
        }

        if (PASS3) {
            __syncthreads();
            float4 yo = *(float4*)&su[ls][g4];
            *(float4*)&ybuf[(base_bl + l0 + ls) * DINNER + d0 + g4] = yo;
        }
    }

    if (!PASS3) {
        *(float4*)&Pbuf[psoff] = make_float4(p[0], p[1], p[2], p[3]);
        *(float4*)&Sbuf[psoff] = make_float4(h[0], h[1], h[2], h[3]);
    }
}

__global__ __launch_bounds__(256) void scan_combine(
    const float* __restrict__ Pbuf, float* __restrict__ Sbuf)
{
    int t = blockIdx.x * 256 + threadIdx.x;
    int b = t >> 15;
    int rem = t & 32767;
    size_t base = (size_t)b * CH * DINNER * DSTATE + rem;
    float H = 0.f;
#pragma unroll 4
    for (int c = 0; c < CH; ++c) {
        size_t off = base + (size_t)c * DINNER * DSTATE;
        float S = Sbuf[off];
        float P = Pbuf[off];
        Sbuf[off] = H;
        H = fmaf(P, H, S);
    }
}

// ---------------------------------------------------------------------------
extern "C" void kernel_launch(void* const* d_in, const int* in_sizes, int n_in,
                              void* d_out, int out_size, void* d_ws, size_t ws_size,
                              hipStream_t stream)
{
    const float* x          = (const float*)d_in[0];
    const float* in_proj_w  = (const float*)d_in[1];
    const float* conv_w     = (const float*)d_in[2];
    const float* conv_b     = (const float*)d_in[3];
    const float* x_proj_w   = (const float*)d_in[4];
    const float* dt_proj_w  = (const float*)d_in[5];
    const float* dt_proj_b  = (const float*)d_in[6];
    const float* A_log      = (const float*)d_in[7];
    const float* Dv         = (const float*)d_in[8];
    const float* out_proj_w = (const float*)d_in[9];
    float* out = (float*)d_out;

    // workspace layout (bytes):
    char* w = (char*)d_ws;
    float* xz   = (float*)(w);                       // 64 MB
    float* u    = (float*)(w + 67108864);            // 32 MB
    float* dbuf = (float*)(w + 100663296);           // 32 MB
    float* xdbl = (float*)(w + 134217728);           // 1.5 MB
    float* Pbuf = (float*)(w + 135790592);           // 8 MB
    float* Sbuf = (float*)(w + 144179200);           // 8 MB  (ends 152567808)
    unsigned short* x2  = (unsigned short*)(w + 152567808);  // 24 MB [4096][3072]
    unsigned short* w2a = (unsigned short*)(w + 177733632);  // 24 MB [4096][3072]
    unsigned short* y2  = x2;                                 // 48 MB [4096][6144] (reuse)
    unsigned short* w2b = (unsigned short*)(w + 135790592);   // 12 MB [1024][6144] over P/S (dead)

    // 1) split x and in_proj_w to tripled-K bf16
    split3_kernel<0><<<(M_ROWS * DMODEL) / 256, 256, 0, stream>>>(x, x2, DMODEL);
    split3_kernel<1><<<(2 * DINNER * DMODEL) / 256, 256, 0, stream>>>(in_proj_w, w2a, DMODEL);
    // 2) in_proj via MFMA: xz[4096][4096]
    {
        dim3 g(4096 / 128, M_ROWS / 128);
        gemm_bf16_nt<128, 128><<<g, 256, 0, stream>>>(x2, w2a, xz, 4096, 3 * DMODEL);
    }
    // 3) conv + silu -> u
    conv_silu_kernel<<<(M_ROWS * DINNER) / 256, 256, 0, stream>>>(xz, conv_w, conv_b, u);
    // 4) x_proj (fp32)
    {
        dim3 g(1, M_ROWS / 32);
        gemm_nt<32, 128, 16, 2, 8, true, 0><<<g, 256, 0, stream>>>(
            u, 2048, x_proj_w, 2048, xdbl, 96, M_ROWS, 96, 2048, nullptr);
    }
    // 5) dt_proj + softplus -> dbuf (fp32)
    {
        dim3 g(2048 / 128, M_ROWS / 128);
        gemm_nt<128, 128, 16, 8, 8, false, 1><<<g, 256, 0, stream>>>(
            xdbl, 96, dt_proj_w, 64, dbuf, 2048, M_ROWS, 2048, 64, dt_proj_b);
    }
    // 6) chunked selective scan
    {
        const int nblk = B_SZ * (DINNER / CPB) * CH;
        scan_chunk<false><<<nblk, 256, 0, stream>>>(dbuf, u, xdbl, A_log, Dv, Pbuf, Sbuf, nullptr);
        scan_combine<<<B_SZ * DINNER * DSTATE / 256, 256, 0, stream>>>(Pbuf, Sbuf);
        scan_chunk<true><<<nblk, 256, 0, stream>>>(dbuf, u, xdbl, A_log, Dv, nullptr, Sbuf, dbuf);
    }
    // 7) gate + split y to tripled-K bf16 (over x2/w2a, now dead)
    gate_split3_kernel<<<(M_ROWS * DINNER) / 256, 256, 0, stream>>>(dbuf, xz, y2);
    // 8) split out_proj_w (over P/S bufs, now dead)
    split3_kernel<1><<<(DMODEL * DINNER) / 256, 256, 0, stream>>>(out_proj_w, w2b, DINNER);
    // 9) out_proj via MFMA: out[4096][1024]
    {
        dim3 g(1024 / 64, M_ROWS / 128);
        gemm_bf16_nt<128, 64><<<g, 256, 0, stream>>>(y2, w2b, out, 1024, 3 * DINNER);
    }
}

// Round 4
// 660.402 us; speedup vs baseline: 2.4705x; 1.2340x over previous
//
#include <hip/hip_runtime.h>
#include <hip/hip_bf16.h>
#include <math.h>

#define B_SZ 2
#define L_SZ 2048
#define DMODEL 1024
#define DINNER 2048
#define DSTATE 16
#define DTRANK 64
#define M_ROWS (B_SZ * L_SZ)   // 4096

#define CH 32
#define CLEN (L_SZ / CH)
#define CPB 64

#define KSPLIT 8
#define KC (DINNER / KSPLIT)   // 256

typedef short shortx8 __attribute__((ext_vector_type(8)));
typedef float floatx4 __attribute__((ext_vector_type(4)));

__device__ __forceinline__ float softplusf(float x) {
    return fmaxf(x, 0.f) + log1pf(expf(-fabsf(x)));
}
__device__ __forceinline__ float siluf(float x) {
    return x * (1.f / (1.f + expf(-x)));
}

__device__ __forceinline__ void async_ld16(const void* g, void* l) {
    __builtin_amdgcn_global_load_lds(
        (__attribute__((address_space(1))) void*)(unsigned long long)g,
        (__attribute__((address_space(3))) void*)(unsigned int)(unsigned long long)l,
        16, 0, 0);
}

// ---------------------------------------------------------------------------
// bf16 MFMA GEMM (m97 structure) on split-bf16 tripled-K buffers.
// ---------------------------------------------------------------------------
template <int BM, int BN>
__global__ __launch_bounds__(256) void gemm_bf16_nt(
    const unsigned short* __restrict__ A,
    const unsigned short* __restrict__ Bm,
    float* __restrict__ C, int ldc, int Kp)
{
    constexpr int TMW = BM / 32;
    constexpr int TNW = BN / 32;
    __shared__ unsigned short As[BM * 32];
    __shared__ unsigned short Bs[BN * 32];

    const int tid = threadIdx.x;
    const int w = tid >> 6;
    const int lane = tid & 63;
    const int wm = w >> 1, wn = w & 1;
    const int m0 = blockIdx.y * BM;
    const int n0 = blockIdx.x * BN;

    const int r4 = lane >> 2;
    const int c8 = (lane & 3) * 8;
    const int lm = lane & 15;
    const int quad = lane >> 4;

    floatx4 acc[TMW][TNW] = {};

    for (int k0 = 0; k0 < Kp; k0 += 32) {
#pragma unroll
        for (int jj = 0; jj < BM / 64; ++jj) {
            int j = w + jj * 4;
            const unsigned short* g = A + (size_t)(m0 + j * 16 + r4) * Kp + k0 + c8;
            async_ld16(g, &As[j * 512]);
        }
#pragma unroll
        for (int jj = 0; jj < BN / 64; ++jj) {
            int j = w + jj * 4;
            const unsigned short* g = Bm + (size_t)(n0 + j * 16 + r4) * Kp + k0 + c8;
            async_ld16(g, &Bs[j * 512]);
        }
        __syncthreads();

        shortx8 af[TMW], bf[TNW];
#pragma unroll
        for (int i = 0; i < TMW; ++i)
            af[i] = *(const shortx8*)&As[(wm * (BM / 2) + i * 16 + lm) * 32 + quad * 8];
#pragma unroll
        for (int j = 0; j < TNW; ++j)
            bf[j] = *(const shortx8*)&Bs[(wn * (BN / 2) + j * 16 + lm) * 32 + quad * 8];
#pragma unroll
        for (int i = 0; i < TMW; ++i)
#pragma unroll
            for (int j = 0; j < TNW; ++j)
                acc[i][j] = __builtin_amdgcn_mfma_f32_16x16x32_bf16(af[i], bf[j], acc[i][j], 0, 0, 0);
        __syncthreads();
    }

#pragma unroll
    for (int i = 0; i < TMW; ++i) {
#pragma unroll
        for (int r = 0; r < 4; ++r) {
            int row = m0 + wm * (BM / 2) + i * 16 + quad * 4 + r;
#pragma unroll
            for (int j = 0; j < TNW; ++j) {
                int col = n0 + wn * (BN / 2) + j * 16 + lm;
                C[(size_t)row * ldc + col] = acc[i][j][r];
            }
        }
    }
}

// ---------------------------------------------------------------------------
// fp32 -> split-bf16 tripled-K.  ORDER 0 (A): [hi|hi|lo]; ORDER 1 (B): [hi|lo|hi]
// ---------------------------------------------------------------------------
template <int ORDER>
__global__ __launch_bounds__(256) void split3_kernel(
    const float* __restrict__ src, unsigned short* __restrict__ dst, int K)
{
    int i = blockIdx.x * 256 + threadIdx.x;
    int m = i / K;
    int k = i - m * K;
    float a = src[i];
    __hip_bfloat16 h = __float2bfloat16(a);
    __hip_bfloat16 l = __float2bfloat16(a - __bfloat162float(h));
    unsigned short hu = *(unsigned short*)&h;
    unsigned short lu = *(unsigned short*)&l;
    unsigned short* row = dst + (size_t)m * 3 * K;
    if (ORDER == 0) { row[k] = hu; row[K + k] = hu; row[2 * K + k] = lu; }
    else           { row[k] = hu; row[K + k] = lu; row[2 * K + k] = hu; }
}

__global__ __launch_bounds__(256) void gate_split3_kernel(
    const float* __restrict__ ybuf, const float* __restrict__ xz,
    unsigned short* __restrict__ dst)
{
    int i = blockIdx.x * 256 + threadIdx.x;
    int d = i % DINNER;
    int bl = i / DINNER;
    float res = xz[(size_t)bl * 4096 + 2048 + d];
    float a = ybuf[i] * siluf(res);
    __hip_bfloat16 h = __float2bfloat16(a);
    __hip_bfloat16 l = __float2bfloat16(a - __bfloat162float(h));
    unsigned short hu = *(unsigned short*)&h;
    unsigned short lu = *(unsigned short*)&l;
    unsigned short* row = dst + (size_t)bl * 3 * DINNER;
    row[d] = hu; row[DINNER + d] = hu; row[2 * DINNER + d] = lu;
}

// ---------------------------------------------------------------------------
// x_proj split-K: Cp[s][M][96] partial = u[:, sKC:(s+1)KC] @ Wx[:, sKC:..]^T
// Block: 256 thr, BM=64, BN=96 (full N), BK=16. Grid (KSPLIT, M/64).
// ---------------------------------------------------------------------------
__global__ __launch_bounds__(256) void xproj_splitk(
    const float* __restrict__ u, const float* __restrict__ Wx,
    float* __restrict__ Cp)
{
    __shared__ float As[16][68];
    __shared__ float Bs[16][100];

    const int tid = threadIdx.x;
    const int ks = blockIdx.x;
    const int m0 = blockIdx.y * 64;
    const int tx = tid & 15;    // n, TN=6
    const int ty = tid >> 4;    // m, TM=4

    float acc[4][6] = {};

    const int arow = tid >> 2;
    const int akk = (tid & 3) * 4;

    for (int k0 = ks * KC; k0 < (ks + 1) * KC; k0 += 16) {
        {
            float4 v = *(const float4*)&u[(size_t)(m0 + arow) * DINNER + k0 + akk];
            As[akk + 0][arow] = v.x;
            As[akk + 1][arow] = v.y;
            As[akk + 2][arow] = v.z;
            As[akk + 3][arow] = v.w;
        }
        for (int idx = tid; idx < 384; idx += 256) {
            int row = idx >> 2;
            int kk = (idx & 3) * 4;
            float4 v = *(const float4*)&Wx[(size_t)row * DINNER + k0 + kk];
            Bs[kk + 0][row] = v.x;
            Bs[kk + 1][row] = v.y;
            Bs[kk + 2][row] = v.z;
            Bs[kk + 3][row] = v.w;
        }
        __syncthreads();

#pragma unroll
        for (int k = 0; k < 16; ++k) {
            float a[4], b[6];
#pragma unroll
            for (int i = 0; i < 4; ++i) a[i] = As[k][ty * 4 + i];
#pragma unroll
            for (int j = 0; j < 6; ++j) b[j] = Bs[k][tx * 6 + j];
#pragma unroll
            for (int i = 0; i < 4; ++i)
#pragma unroll
                for (int j = 0; j < 6; ++j) acc[i][j] = fmaf(a[i], b[j], acc[i][j]);
        }
        __syncthreads();
    }

    float* outp = Cp + ((size_t)ks * M_ROWS + m0) * 96;
#pragma unroll
    for (int i = 0; i < 4; ++i)
#pragma unroll
        for (int j = 0; j < 6; ++j)
            outp[(ty * 4 + i) * 96 + tx * 6 + j] = acc[i][j];
}

__global__ __launch_bounds__(256) void xproj_reduce(
    const float* __restrict__ Cp, float* __restrict__ xdbl)
{
    int i = blockIdx.x * 256 + threadIdx.x;    // 0 .. M*96-1
    float s = 0.f;
#pragma unroll
    for (int c = 0; c < KSPLIT; ++c)
        s += Cp[(size_t)c * M_ROWS * 96 + i];
    xdbl[i] = s;
}

// ---------------------------------------------------------------------------
// fp32 GEMM (still used for dt_proj, K=64)
// ---------------------------------------------------------------------------
template <int BM, int BN, int BK, int TM, int TN, bool BOUND_N, int EPI>
__global__ __launch_bounds__(256) void gemm_nt(
    const float* __restrict__ A, int lda,
    const float* __restrict__ Bmat, int ldb,
    float* __restrict__ C, int ldc,
    int M, int N, int K, const float* __restrict__ bias)
{
    __shared__ float As[BK][BM + 4];
    __shared__ float Bs[BK][BN + 4];

    const int tid = threadIdx.x;
    const int tx = tid % (BN / TN);
    const int ty = tid / (BN / TN);
    const int m0 = blockIdx.y * BM;
    const int n0 = blockIdx.x * BN;

    float acc[TM][TN];
#pragma unroll
    for (int i = 0; i < TM; ++i)
#pragma unroll
        for (int j = 0; j < TN; ++j) acc[i][j] = 0.f;

    for (int k0 = 0; k0 < K; k0 += BK) {
        for (int idx = tid * 4; idx < BM * BK; idx += 256 * 4) {
            int row = idx / BK;
            int kk = idx % BK;
            float4 v = *(const float4*)&A[(size_t)(m0 + row) * lda + k0 + kk];
            As[kk + 0][row] = v.x;
            As[kk + 1][row] = v.y;
            As[kk + 2][row] = v.z;
            As[kk + 3][row] = v.w;
        }
        for (int idx = tid * 4; idx < BN * BK; idx += 256 * 4) {
            int row = idx / BK;
            int kk = idx % BK;
            float4 v;
            if (!BOUND_N || (n0 + row) < N)
                v = *(const float4*)&Bmat[(size_t)(n0 + row) * ldb + k0 + kk];
            else
                v = make_float4(0.f, 0.f, 0.f, 0.f);
            Bs[kk + 0][row] = v.x;
            Bs[kk + 1][row] = v.y;
            Bs[kk + 2][row] = v.z;
            Bs[kk + 3][row] = v.w;
        }
        __syncthreads();

#pragma unroll
        for (int k = 0; k < BK; ++k) {
            float a[TM], b[TN];
#pragma unroll
            for (int i = 0; i < TM; ++i) a[i] = As[k][ty * TM + i];
#pragma unroll
            for (int j = 0; j < TN; ++j) b[j] = Bs[k][tx * TN + j];
#pragma unroll
            for (int i = 0; i < TM; ++i)
#pragma unroll
                for (int j = 0; j < TN; ++j) acc[i][j] = fmaf(a[i], b[j], acc[i][j]);
        }
        __syncthreads();
    }

#pragma unroll
    for (int i = 0; i < TM; ++i) {
        int m = m0 + ty * TM + i;
#pragma unroll
        for (int j = 0; j < TN; ++j) {
            int n = n0 + tx * TN + j;
            if (BOUND_N && n >= N) continue;
            float v = acc[i][j];
            if (EPI == 1) v = softplusf(v + bias[n]);
            C[(size_t)m * ldc + n] = v;
        }
    }
}

// ---------------------------------------------------------------------------
__global__ __launch_bounds__(256) void conv_silu_kernel(
    const float* __restrict__ xz, const float* __restrict__ cw,
    const float* __restrict__ cb, float* __restrict__ u)
{
    int i = blockIdx.x * 256 + threadIdx.x;
    int d = i % DINNER;
    int bl = i / DINNER;
    int b = bl / L_SZ;
    int l = bl % L_SZ;
    float acc = cb[d];
#pragma unroll
    for (int k = 0; k < 4; ++k) {
        int ls = l + k - 3;
        if (ls >= 0)
            acc = fmaf(xz[(size_t)(b * L_SZ + ls) * 4096 + d], cw[d * 4 + k], acc);
    }
    u[i] = siluf(acc);
}

// ---------------------------------------------------------------------------
// Chunked selective scan (3 passes).
// ---------------------------------------------------------------------------
template <bool PASS3>
__global__ __launch_bounds__(256) void scan_chunk(
    const float* __restrict__ dbuf, const float* __restrict__ ubuf,
    const float* __restrict__ xdbl, const float* __restrict__ A_log,
    const float* __restrict__ Dv,
    float* __restrict__ Pbuf, float* __restrict__ Sbuf,
    float* __restrict__ ybuf)
{
    __shared__ float sd[16][CPB];
    __shared__ float su[16][CPB];
    __shared__ float sB[16][DSTATE];
    __shared__ float sC[16][DSTATE];

    const int tid = threadIdx.x;
    const int c    = blockIdx.x % CH;
    const int dblk = (blockIdx.x / CH) % (DINNER / CPB);
    const int b    = blockIdx.x / (CH * (DINNER / CPB));
    const int d0 = dblk * CPB;
    const int dg = tid >> 2;
    const int q  = tid & 3;
    const int d  = d0 + dg;
    const size_t base_bl = (size_t)b * L_SZ + (size_t)c * CLEN;

    float Ac[4], h[4], p[4];
#pragma unroll
    for (int j = 0; j < 4; ++j) {
        Ac[j] = -expf(A_log[d * DSTATE + 4 * q + j]);
        p[j] = 1.f;
    }
    const size_t psoff = (((size_t)b * CH + c) * DINNER + d0) * DSTATE + (size_t)tid * 4;
    if (PASS3) {
        float4 h0 = *(const float4*)&Sbuf[psoff];
        h[0] = h0.x; h[1] = h0.y; h[2] = h0.z; h[3] = h0.w;
    } else {
        h[0] = h[1] = h[2] = h[3] = 0.f;
    }
    const float Dd = PASS3 ? Dv[d] : 0.f;

    const int ls = tid >> 4;
    const int g4 = (tid & 15) * 4;
    const int ln = tid & 15;

    float4 r_d = *(const float4*)&dbuf[(base_bl + ls) * DINNER + d0 + g4];
    float4 r_u = *(const float4*)&ubuf[(base_bl + ls) * DINNER + d0 + g4];
    float r_B = xdbl[(base_bl + ls) * 96 + 64 + ln];
    float r_C = xdbl[(base_bl + ls) * 96 + 80 + ln];

    for (int l0 = 0; l0 < CLEN; l0 += 16) {
        __syncthreads();
        *(float4*)&sd[ls][g4] = r_d;
        *(float4*)&su[ls][g4] = r_u;
        sB[ls][ln] = r_B;
        sC[ls][ln] = r_C;
        __syncthreads();

        if (l0 + 16 < CLEN) {
            r_d = *(const float4*)&dbuf[(base_bl + l0 + 16 + ls) * DINNER + d0 + g4];
            r_u = *(const float4*)&ubuf[(base_bl + l0 + 16 + ls) * DINNER + d0 + g4];
            r_B = xdbl[(base_bl + l0 + 16 + ls) * 96 + 64 + ln];
            r_C = xdbl[(base_bl + l0 + 16 + ls) * 96 + 80 + ln];
        }

#pragma unroll
        for (int s = 0; s < 16; ++s) {
            float dl = sd[s][dg];
            float ul = su[s][dg];
            float4 Bv = *(float4*)&sB[s][4 * q];
            float dbu = dl * ul;
            float dA0 = expf(dl * Ac[0]);
            float dA1 = expf(dl * Ac[1]);
            float dA2 = expf(dl * Ac[2]);
            float dA3 = expf(dl * Ac[3]);
            h[0] = fmaf(dA0, h[0], dbu * Bv.x);
            h[1] = fmaf(dA1, h[1], dbu * Bv.y);
            h[2] = fmaf(dA2, h[2], dbu * Bv.z);
            h[3] = fmaf(dA3, h[3], dbu * Bv.w);
            if (!PASS3) {
                p[0] *= dA0; p[1] *= dA1; p[2] *= dA2; p[3] *= dA3;
            } else {
                float4 Cv = *(float4*)&sC[s][4 * q];
                float y = h[0] * Cv.x + h[1] * Cv.y + h[2] * Cv.z + h[3] * Cv.w;
                y += __shfl_xor(y, 1);
                y += __shfl_xor(y, 2);
                if (q == 0) su[s][dg] = fmaf(ul, Dd, y);
            }
        }

        if (PASS3) {
            __syncthreads();
            float4 yo = *(float4*)&su[ls][g4];
            *(float4*)&ybuf[(base_bl + l0 + ls) * DINNER + d0 + g4] = yo;
        }
    }

    if (!PASS3) {
        *(float4*)&Pbuf[psoff] = make_float4(p[0], p[1], p[2], p[3]);
        *(float4*)&Sbuf[psoff] = make_float4(h[0], h[1], h[2], h[3]);
    }
}

__global__ __launch_bounds__(256) void scan_combine(
    const float* __restrict__ Pbuf, float* __restrict__ Sbuf)
{
    int t = blockIdx.x * 256 + threadIdx.x;
    int b = t >> 15;
    int rem = t & 32767;
    size_t base = (size_t)b * CH * DINNER * DSTATE + rem;
    float H = 0.f;
#pragma unroll 4
    for (int c = 0; c < CH; ++c) {
        size_t off = base + (size_t)c * DINNER * DSTATE;
        float S = Sbuf[off];
        float P = Pbuf[off];
        Sbuf[off] = H;
        H = fmaf(P, H, S);
    }
}

// ---------------------------------------------------------------------------
extern "C" void kernel_launch(void* const* d_in, const int* in_sizes, int n_in,
                              void* d_out, int out_size, void* d_ws, size_t ws_size,
                              hipStream_t stream)
{
    const float* x          = (const float*)d_in[0];
    const float* in_proj_w  = (const float*)d_in[1];
    const float* conv_w     = (const float*)d_in[2];
    const float* conv_b     = (const float*)d_in[3];
    const float* x_proj_w   = (const float*)d_in[4];
    const float* dt_proj_w  = (const float*)d_in[5];
    const float* dt_proj_b  = (const float*)d_in[6];
    const float* A_log      = (const float*)d_in[7];
    const float* Dv         = (const float*)d_in[8];
    const float* out_proj_w = (const float*)d_in[9];
    float* out = (float*)d_out;

    // workspace layout (bytes):
    char* w = (char*)d_ws;
    float* xz   = (float*)(w);                       // 64 MB
    float* u    = (float*)(w + 67108864);            // 32 MB
    float* dbuf = (float*)(w + 100663296);           // 32 MB
    float* xdbl = (float*)(w + 134217728);           // 1.5 MB
    float* Pbuf = (float*)(w + 135790592);           // 8 MB
    float* Sbuf = (float*)(w + 144179200);           // 8 MB
    unsigned short* x2  = (unsigned short*)(w + 152567808);  // 24 MB region
    unsigned short* w2a = (unsigned short*)(w + 177733632);  // 24 MB
    unsigned short* y2  = x2;                                 // 48 MB (stage 7+)
    unsigned short* w2b = (unsigned short*)(w + 135790592);   // over P/S (dead at 8+)
    float* Cp = (float*)(w + 152567808);             // 12.6 MB (x2 region, dead at stage 4)

    // 1) split x and in_proj_w to tripled-K bf16
    split3_kernel<0><<<(M_ROWS * DMODEL) / 256, 256, 0, stream>>>(x, x2, DMODEL);
    split3_kernel<1><<<(2 * DINNER * DMODEL) / 256, 256, 0, stream>>>(in_proj_w, w2a, DMODEL);
    // 2) in_proj via MFMA
    {
        dim3 g(4096 / 128, M_ROWS / 128);
        gemm_bf16_nt<128, 128><<<g, 256, 0, stream>>>(x2, w2a, xz, 4096, 3 * DMODEL);
    }
    // 3) conv + silu -> u
    conv_silu_kernel<<<(M_ROWS * DINNER) / 256, 256, 0, stream>>>(xz, conv_w, conv_b, u);
    // 4) x_proj via split-K (x2 region is dead here; reused for partials)
    {
        dim3 g(KSPLIT, M_ROWS / 64);
        xproj_splitk<<<g, 256, 0, stream>>>(u, x_proj_w, Cp);
        xproj_reduce<<<(M_ROWS * 96) / 256, 256, 0, stream>>>(Cp, xdbl);
    }
    // 5) dt_proj + softplus -> dbuf (fp32, K=64)
    {
        dim3 g(2048 / 128, M_ROWS / 128);
        gemm_nt<128, 128, 16, 8, 8, false, 1><<<g, 256, 0, stream>>>(
            xdbl, 96, dt_proj_w, 64, dbuf, 2048, M_ROWS, 2048, 64, dt_proj_b);
    }
    // 6) chunked selective scan
    {
        const int nblk = B_SZ * (DINNER / CPB) * CH;
        scan_chunk<false><<<nblk, 256, 0, stream>>>(dbuf, u, xdbl, A_log, Dv, Pbuf, Sbuf, nullptr);
        scan_combine<<<B_SZ * DINNER * DSTATE / 256, 256, 0, stream>>>(Pbuf, Sbuf);
        scan_chunk<true><<<nblk, 256, 0, stream>>>(dbuf, u, xdbl, A_log, Dv, nullptr, Sbuf, dbuf);
    }
    // 7) gate + split y (x2/Cp region reused as y2)
    gate_split3_kernel<<<(M_ROWS * DINNER) / 256, 256, 0, stream>>>(dbuf, xz, y2);
    // 8) split out_proj_w (over P/S bufs, dead now)
    split3_kernel<1><<<(DMODEL * DINNER) / 256, 256, 0, stream>>>(out_proj_w, w2b, DINNER);
    // 9) out_proj via MFMA
    {
        dim3 g(1024 / 64, M_ROWS / 128);
        gemm_bf16_nt<128, 64><<<g, 256, 0, stream>>>(y2, w2b, out, 1024, 3 * DINNER);
    }
}